// Round 14
// baseline (3341.610 us; speedup 1.0000x reference)
//
#include <hip/hip_runtime.h>
#include <hip/hip_bf16.h>

#define TT  512
#define BB  64
#define NII 1024
#define NHH 1024
#define NBLK 256

typedef __attribute__((ext_vector_type(8))) short bf16x8;
typedef __attribute__((ext_vector_type(4))) float f32x4;
typedef unsigned long long u64;

// ws layout: [wpk 16M][flags 16K][hpp 256K][xpk/ring 64M][gx 256M]
// xpk doubles as the H ring after xproj_gemm consumes it (verified r12).
#define WPK_BYTES  (16ull << 20)
#define FLG_BYTES  (16384ull)
#define HPP_BYTES  (256ull << 10)
#define XPK_BYTES  (64ull << 20)
#define GX_BYTES   (256ull << 20)
#define HBUF_SHORTS 32768ull

#define MFMA16 __builtin_amdgcn_mfma_f32_16x16x32_bf16
#define LD_AG(p)    __hip_atomic_load((p),  __ATOMIC_RELAXED, __HIP_MEMORY_SCOPE_AGENT)
#define ST_AG(p, v) __hip_atomic_store((p), (v), __ATOMIC_RELAXED, __HIP_MEMORY_SCOPE_AGENT)

__device__ __forceinline__ float fast_sigmoid(float x) {
    return __builtin_amdgcn_rcpf(1.0f + __expf(-x));
}
__device__ __forceinline__ float fast_tanh(float x) {
    float e = __expf(2.0f * x);
    return 1.0f - 2.0f * __builtin_amdgcn_rcpf(e + 1.0f);
}
__device__ __forceinline__ short f2bf(float f) {
    union { __hip_bfloat16 b; short s; } u; u.b = __float2bfloat16(f); return u.s;
}
__device__ __forceinline__ float bf2f(short h) {
    union { unsigned u; float f; } v; v.u = ((unsigned)(unsigned short)h) << 16; return v.f;
}

// pipelined coherent 16B load (modes 0/1 fallback only)
__device__ __forceinline__ bf16x8 ld_coh16(const short* p) {
    const u64* q = (const u64*)p;
    u64 a = LD_AG(q);
    u64 b = LD_AG(q + 1);
    union { u64 u[2]; bf16x8 v; } u;
    u.u[0] = a; u.u[1] = b; return u.v;
}

// ---------------------------------------------------------------------------
// Pack weights, B-fragment-major bf16, 32 gate-cols per c-block (verified r8-r13).
// ---------------------------------------------------------------------------
__global__ __launch_bounds__(256)
void pack_weights_kernel(const float* __restrict__ Wxf, const float* __restrict__ Whf,
                         const float* __restrict__ Wxi, const float* __restrict__ Whi,
                         const float* __restrict__ Wxc, const float* __restrict__ Whc,
                         const float* __restrict__ Wxo, const float* __restrict__ Who,
                         short* __restrict__ wpk)
{
    const int c = blockIdx.x;
    const int t = threadIdx.x;
    const float* Wx[4] = { Wxf, Wxi, Wxc, Wxo };
    const float* Wh[4] = { Whf, Whi, Whc, Who };

    for (int i = 0; i < 32; ++i) {
        const int d   = t + i * 256;
        const int kkf = d >> 7;
        const int nt  = (d >> 6) & 1;
        const int l   = d & 63;
        const int n   = nt * 16 + (l & 15);
        const int g   = n >> 3;
        const int col = c * 8 + (n & 7);
        const int kf0 = kkf * 32 + (l >> 4) * 8;
        const float* src = (kf0 < 1024) ? (Wx[g] + (size_t)kf0 * NHH + col)
                                        : (Wh[g] + (size_t)(kf0 - 1024) * NHH + col);
        short v[8];
        #pragma unroll
        for (int e = 0; e < 8; ++e) v[e] = f2bf(src[(size_t)e * NHH]);
        *reinterpret_cast<bf16x8*>(wpk + ((size_t)c * 8192 + d) * 8) =
            *reinterpret_cast<bf16x8*>(v);
    }
}

// ---------------------------------------------------------------------------
// Pack x into per-half A-fragments (verified r8-r13).
// ---------------------------------------------------------------------------
__global__ __launch_bounds__(256)
void pack_x_kernel(const float* __restrict__ x, short* __restrict__ xpk)
{
    const int t = blockIdx.x;
    const float* xt = x + (size_t)t * BB * NII;
    short* dst = xpk + (size_t)t * 65536;

    for (int i = 0; i < 32; ++i) {
        const int d  = threadIdx.x + i * 256;
        const int s  = d >> 12;
        const int mi = (d >> 11) & 1;
        const int kk = (d >> 6) & 31;
        const int l  = d & 63;
        const int m  = s * 32 + mi * 16 + (l & 15);
        const int k0 = kk * 32 + ((l >> 4) << 3);
        const float* sp = xt + (size_t)m * NII + k0;
        f32x4 a0 = *reinterpret_cast<const f32x4*>(sp);
        f32x4 a1 = *reinterpret_cast<const f32x4*>(sp + 4);
        short v[8];
        #pragma unroll
        for (int e = 0; e < 4; ++e) { v[e] = f2bf(a0[e]); v[4 + e] = f2bf(a1[e]); }
        *reinterpret_cast<bf16x8*>(dst + (size_t)d * 8) = *reinterpret_cast<bf16x8*>(v);
    }
}

// ---------------------------------------------------------------------------
// x_proj GEMM v3 (round 14): ONE timestep per block, 512 blocks x 512 thr.
// A t-slice (128 KiB) staged ONCE into LDS; weights streamed from global
// (L2/L1-served, 4-way L1 reuse across the 4 (s,mi) waves per c-half).
// A-traffic: 8 GB (r12 geometry) -> 64 MB. Output layout identical to r12.
// Wave w: (s,mi) = ((w&3)>>1, w&1); c-range = (w>>2)*64 .. +64.
// ---------------------------------------------------------------------------
__global__ __launch_bounds__(512)
void xproj_gemm(const short* __restrict__ xpk, const short* __restrict__ wpk,
                short* __restrict__ gx)
{
    __shared__ short lds_a[65536];   // 128 KiB: full xpk[t] slice

    const int tid = threadIdx.x;
    const int w = tid >> 6, l = tid & 63;
    const int t = blockIdx.x;
    const int q = w & 3;             // (s*2 + mi)
    const int s = q >> 1, mi = q & 1;
    const int c0 = (w >> 2) * 64;

    // stage A: 65536 shorts = 8192 x 16B chunks / 512 threads = 16 iters
    {
        const short* src = xpk + (size_t)t * 65536;
        #pragma unroll
        for (int i = 0; i < 16; ++i) {
            const int ch = tid + i * 512;
            *reinterpret_cast<bf16x8*>(&lds_a[(size_t)ch * 8]) =
                *reinterpret_cast<const bf16x8*>(&src[(size_t)ch * 8]);
        }
    }
    __syncthreads();

    const short* abase = &lds_a[(size_t)(q * 32) * 512 + (size_t)l * 8];

    for (int c = c0; c < c0 + 64; ++c) {
        const short* wg = wpk + (size_t)c * 65536 + (size_t)l * 8;  // x-half base
        f32x4 a00 = {0,0,0,0}, a01 = {0,0,0,0}, a10 = {0,0,0,0}, a11 = {0,0,0,0};
        const short* ap = abase;
        const short* wl = wg;
        #pragma unroll 4
        for (int kk = 0; kk < 32; kk += 2) {
            bf16x8 A0  = *reinterpret_cast<const bf16x8*>(ap);
            bf16x8 B00 = *reinterpret_cast<const bf16x8*>(wl);
            bf16x8 B01 = *reinterpret_cast<const bf16x8*>(wl + 512);
            bf16x8 A1  = *reinterpret_cast<const bf16x8*>(ap + 512);
            bf16x8 B10 = *reinterpret_cast<const bf16x8*>(wl + 1024);
            bf16x8 B11 = *reinterpret_cast<const bf16x8*>(wl + 1536);
            a00 = MFMA16(A0, B00, a00, 0, 0, 0);
            a01 = MFMA16(A0, B01, a01, 0, 0, 0);
            a10 = MFMA16(A1, B10, a10, 0, 0, 0);
            a11 = MFMA16(A1, B11, a11, 0, 0, 0);
            ap += 1024; wl += 2048;
        }
        short o[8];
        o[0] = f2bf(a00[0] + a10[0]); o[1] = f2bf(a00[1] + a10[1]);
        o[2] = f2bf(a00[2] + a10[2]); o[3] = f2bf(a00[3] + a10[3]);
        o[4] = f2bf(a01[0] + a11[0]); o[5] = f2bf(a01[1] + a11[1]);
        o[6] = f2bf(a01[2] + a11[2]); o[7] = f2bf(a01[3] + a11[3]);
        short* dst = gx + ((((size_t)t * 2 + s) * 128 + c) * 2 + mi) * 512
                   + (size_t)l * 8;
        *reinterpret_cast<bf16x8*>(dst) = *reinterpret_cast<bf16x8*>(o);
    }
}

// ---------------------------------------------------------------------------
// x-half compute (modes 0/1 fallback; verified r9-r12).
// ---------------------------------------------------------------------------
__device__ __forceinline__ void compute_x_half(
    int t, int mi, int l, int s, int use_xpk,
    const float* __restrict__ x, const short* __restrict__ xpk,
    const short* lds_w, float* rdst)
{
    f32x4 a00 = {0,0,0,0}, a01 = {0,0,0,0}, a10 = {0,0,0,0}, a11 = {0,0,0,0};
    const short* wl = lds_w + (size_t)l * 8;
    if (use_xpk) {
        const short* ap = xpk + (size_t)t * 65536
                        + (((size_t)(s * 2 + mi)) * 32) * 512 + (size_t)l * 8;
        #pragma unroll 4
        for (int kk = 0; kk < 32; kk += 2) {
            bf16x8 A0  = *reinterpret_cast<const bf16x8*>(ap);
            bf16x8 B00 = *reinterpret_cast<const bf16x8*>(wl);
            bf16x8 B01 = *reinterpret_cast<const bf16x8*>(wl + 512);
            bf16x8 A1  = *reinterpret_cast<const bf16x8*>(ap + 512);
            bf16x8 B10 = *reinterpret_cast<const bf16x8*>(wl + 1024);
            bf16x8 B11 = *reinterpret_cast<const bf16x8*>(wl + 1536);
            a00 = MFMA16(A0, B00, a00, 0, 0, 0);
            a01 = MFMA16(A0, B01, a01, 0, 0, 0);
            a10 = MFMA16(A1, B10, a10, 0, 0, 0);
            a11 = MFMA16(A1, B11, a11, 0, 0, 0);
            ap += 1024; wl += 2048;
        }
    } else {
        const float* apf = x + ((size_t)t * BB + (size_t)(s * 32 + mi * 16 + (l & 15))) * NII
                         + ((l >> 4) << 3);
        #pragma unroll 4
        for (int kk = 0; kk < 32; kk += 2) {
            f32x4 f0 = *reinterpret_cast<const f32x4*>(apf);
            f32x4 f1 = *reinterpret_cast<const f32x4*>(apf + 4);
            bf16x8 B00 = *reinterpret_cast<const bf16x8*>(wl);
            bf16x8 B01 = *reinterpret_cast<const bf16x8*>(wl + 512);
            f32x4 f2 = *reinterpret_cast<const f32x4*>(apf + 32);
            f32x4 f3 = *reinterpret_cast<const f32x4*>(apf + 36);
            bf16x8 B10 = *reinterpret_cast<const bf16x8*>(wl + 1024);
            bf16x8 B11 = *reinterpret_cast<const bf16x8*>(wl + 1536);
            bf16x8 A0, A1;
            A0[0]=f2bf(f0[0]); A0[1]=f2bf(f0[1]); A0[2]=f2bf(f0[2]); A0[3]=f2bf(f0[3]);
            A0[4]=f2bf(f1[0]); A0[5]=f2bf(f1[1]); A0[6]=f2bf(f1[2]); A0[7]=f2bf(f1[3]);
            A1[0]=f2bf(f2[0]); A1[1]=f2bf(f2[1]); A1[2]=f2bf(f2[2]); A1[3]=f2bf(f2[3]);
            A1[4]=f2bf(f3[0]); A1[5]=f2bf(f3[1]); A1[6]=f2bf(f3[2]); A1[7]=f2bf(f3[3]);
            a00 = MFMA16(A0, B00, a00, 0, 0, 0);
            a01 = MFMA16(A0, B01, a01, 0, 0, 0);
            a10 = MFMA16(A1, B10, a10, 0, 0, 0);
            a11 = MFMA16(A1, B11, a11, 0, 0, 0);
            apf += 64; wl += 2048;
        }
    }
    rdst[0] = a00[0] + a10[0]; rdst[1] = a00[1] + a10[1];
    rdst[2] = a00[2] + a10[2]; rdst[3] = a00[3] + a10[3];
    rdst[4] = a01[0] + a11[0]; rdst[5] = a01[1] + a11[1];
    rdst[6] = a01[2] + a11[2]; rdst[7] = a01[3] + a11[3];
}

// ---------------------------------------------------------------------------
// Persistent LSTM — byte-identical to round 12 (best verified: 2.09 ms).
// ---------------------------------------------------------------------------
__global__ __launch_bounds__(256, 1)
void lstm_persistent(const float* __restrict__ x,
                     const short* __restrict__ xpk,
                     const short* __restrict__ wpk,
                     const short* __restrict__ gx,
                     const float* __restrict__ bfv, const float* __restrict__ biv,
                     const float* __restrict__ bcv, const float* __restrict__ bov,
                     float* __restrict__ out,
                     short* hpp,
                     short* ring,
                     unsigned* flags,
                     int mode)
{
    __shared__ short lds_w[64 * 2 * 64 * 8];   // 128 KiB weights
    __shared__ float redx[2][2][64][8];        // modes 0/1 only
    __shared__ float redh[4][64][8];
    __shared__ short hstage[256];
    __shared__ int   lds_epoch;

    const int tid = threadIdx.x;
    const int w   = tid >> 6;
    const int l   = tid & 63;
    const int c   = blockIdx.x >> 1;
    const int s   = blockIdx.x & 1;

    unsigned* flags_s = flags + s * 2048;      // 128 flags x 64 B stride

    if (mode == 2) {
        const short* wsrc = wpk + (size_t)c * 65536 + 32768;   // h-half only
        #pragma unroll
        for (int i = 0; i < 16; ++i) {
            const int ch = tid + i * 256;
            *reinterpret_cast<bf16x8*>(&lds_w[(size_t)ch * 8]) =
                *reinterpret_cast<const bf16x8*>(&wsrc[(size_t)ch * 8]);
        }
    } else {
        const short* wsrc = wpk + (size_t)c * 65536;
        #pragma unroll
        for (int i = 0; i < 32; ++i) {
            const int ch = tid + i * 256;
            *reinterpret_cast<bf16x8*>(&lds_w[(size_t)ch * 8]) =
                *reinterpret_cast<const bf16x8*>(&wsrc[(size_t)ch * 8]);
        }
    }
    if (tid == 0) lds_epoch = -1;

    const int m_loc = tid >> 3;
    const int jc    = tid & 7;
    const int mi2   = m_loc >> 4, ml = m_loc & 15;
    const int lb    = (ml >> 2) << 4, lr = ml & 3;
    const int jcol  = c * 8 + jc;
    const int mrow  = s * 32 + m_loc;
    int lanes[4], es[4];
    #pragma unroll
    for (int g = 0; g < 4; ++g) { lanes[g] = lb + (g & 1) * 8 + jc; es[g] = (g >> 1) * 4 + lr; }

    float B4[4];
    B4[0] = bfv[jcol]; B4[1] = biv[jcol]; B4[2] = bcv[jcol]; B4[3] = bov[jcol];
    float cstate = 0.0f;
    __syncthreads();

    // prologues
    float gxv[4] = {0.f, 0.f, 0.f, 0.f};
    if (mode == 2) {
        const short* gsl = gx + ((((size_t)0 * 2 + s) * 128 + c) * 2 + mi2) * 512;
        #pragma unroll
        for (int g = 0; g < 4; ++g) gxv[g] = bf2f(gsl[(size_t)lanes[g] * 8 + es[g]]);
    } else if (w < 2) {
        compute_x_half(0, w & 1, l, s, mode, x, xpk, lds_w, &redx[0][w & 1][l][0]);
    }

    #pragma unroll 1
    for (int t = 0; t < TT; ++t) {
        const short* rcur = (mode == 2)
            ? ring + (size_t)t * 65536 + (size_t)s * 32768
            : hpp + ((size_t)((t & 1) * 2 + s)) * HBUF_SHORTS;
        short* rnxt = (mode == 2)
            ? ring + (size_t)(t + 1) * 65536 + (size_t)s * 32768
            : hpp + ((size_t)(((t + 1) & 1) * 2 + s)) * HBUF_SHORTS;

        if (mode == 2) {
            if (w == 2) {
                const unsigned tv = (unsigned)t;
                for (;;) {
                    unsigned v0 = LD_AG(flags_s + (size_t)l * 16);
                    unsigned v1 = LD_AG(flags_s + (size_t)(l + 64) * 16);
                    if (__all((v0 >= tv) & (v1 >= tv))) break;
                    __builtin_amdgcn_s_sleep(1);
                }
                if (l == 0) *((volatile int*)&lds_epoch) = t;
            } else {
                while (*((volatile int*)&lds_epoch) < t) { }
            }
            asm volatile("" ::: "memory");   // keep H loads below the wait

            const int mi = w & 1, ki = w >> 1;
            f32x4 a00 = {0,0,0,0}, a01 = {0,0,0,0}, a10 = {0,0,0,0}, a11 = {0,0,0,0};
            const short* ap = rcur + ((size_t)(mi * 32 + ki * 16) * 64 + l) * 8;
            const short* wl = &lds_w[(size_t)ki * 16384 + (size_t)l * 8];
            #pragma unroll 4
            for (int kk = 0; kk < 16; kk += 2) {
                bf16x8 A0  = *reinterpret_cast<const bf16x8*>(ap);        // plain cached
                bf16x8 B00 = *reinterpret_cast<const bf16x8*>(wl);
                bf16x8 B01 = *reinterpret_cast<const bf16x8*>(wl + 512);
                bf16x8 A1  = *reinterpret_cast<const bf16x8*>(ap + 512);  // plain cached
                bf16x8 B10 = *reinterpret_cast<const bf16x8*>(wl + 1024);
                bf16x8 B11 = *reinterpret_cast<const bf16x8*>(wl + 1536);
                a00 = MFMA16(A0, B00, a00, 0, 0, 0);
                a01 = MFMA16(A0, B01, a01, 0, 0, 0);
                a10 = MFMA16(A1, B10, a10, 0, 0, 0);
                a11 = MFMA16(A1, B11, a11, 0, 0, 0);
                ap += 1024; wl += 2048;
            }
            float* r = &redh[w][l][0];
            r[0] = a00[0] + a10[0]; r[1] = a00[1] + a10[1];
            r[2] = a00[2] + a10[2]; r[3] = a00[3] + a10[3];
            r[4] = a01[0] + a11[0]; r[5] = a01[1] + a11[1];
            r[6] = a01[2] + a11[2]; r[7] = a01[3] + a11[3];
        } else if (w >= 2) {
            const int mi = w & 1;
            if (mi == 0) {
                const unsigned tv = (unsigned)t;
                for (;;) {
                    unsigned v0 = LD_AG(flags_s + (size_t)l * 16);
                    unsigned v1 = LD_AG(flags_s + (size_t)(l + 64) * 16);
                    if (__all((v0 >= tv) & (v1 >= tv))) break;
                    __builtin_amdgcn_s_sleep(1);
                }
                if (l == 0) *((volatile int*)&lds_epoch) = t;
            } else {
                while (*((volatile int*)&lds_epoch) < t) { }
            }
            asm volatile("" ::: "memory");

            f32x4 a00 = {0,0,0,0}, a01 = {0,0,0,0}, a10 = {0,0,0,0}, a11 = {0,0,0,0};
            const short* ap = rcur + ((size_t)(mi * 32)) * 512 + (size_t)l * 8;
            const short* wl = &lds_w[(size_t)32768 + (size_t)l * 8];
            #pragma unroll 4
            for (int kk = 0; kk < 32; kk += 2) {
                bf16x8 A0  = ld_coh16(ap);
                bf16x8 B00 = *reinterpret_cast<const bf16x8*>(wl);
                bf16x8 B01 = *reinterpret_cast<const bf16x8*>(wl + 512);
                bf16x8 A1  = ld_coh16(ap + 512);
                bf16x8 B10 = *reinterpret_cast<const bf16x8*>(wl + 1024);
                bf16x8 B11 = *reinterpret_cast<const bf16x8*>(wl + 1536);
                a00 = MFMA16(A0, B00, a00, 0, 0, 0);
                a01 = MFMA16(A0, B01, a01, 0, 0, 0);
                a10 = MFMA16(A1, B10, a10, 0, 0, 0);
                a11 = MFMA16(A1, B11, a11, 0, 0, 0);
                ap += 1024; wl += 2048;
            }
            float* r = &redh[2 + mi][l][0];
            r[0] = a00[0] + a10[0]; r[1] = a00[1] + a10[1];
            r[2] = a00[2] + a10[2]; r[3] = a00[3] + a10[3];
            r[4] = a01[0] + a11[0]; r[5] = a01[1] + a11[1];
            r[6] = a01[2] + a11[2]; r[7] = a01[3] + a11[3];
        } else {
            if (t + 1 < TT)
                compute_x_half(t + 1, w & 1, l, s, mode, x, xpk, lds_w,
                               &redx[(t + 1) & 1][w & 1][l][0]);
        }
        __syncthreads();

        // epilogue
        float gv[4];
        #pragma unroll
        for (int g = 0; g < 4; ++g) {
            const int lane = lanes[g], e = es[g];
            float xterm = (mode == 2) ? (gxv[g] + redh[mi2][lane][e])
                                      : redx[t & 1][mi2][lane][e];
            gv[g] = xterm + redh[2 + mi2][lane][e] + B4[g];
        }
        const float F  = fast_sigmoid(gv[0]);
        const float I  = fast_sigmoid(gv[1]);
        const float Ct = fast_tanh(gv[2]);
        const float O  = fast_sigmoid(gv[3]);
        cstate = F * cstate + I * Ct;
        const float hn = O * fast_tanh(cstate);
        hstage[tid] = f2bf(hn);
        __syncthreads();

        // wave0 publishes packed H + flag (protocol verified r3-r12)
        if (w == 0 && t < TT - 1) {
            if (l < 32) {
                const int mi3 = l >> 4, ml3 = l & 15;
                const u64 v0 = ((const u64*)hstage)[l * 2];
                const u64 v1 = ((const u64*)hstage)[l * 2 + 1];
                const size_t sh = ((size_t)(mi3 * 32 + (c >> 2)) * 64
                                   + (size_t)((c & 3) * 16 + ml3)) * 8;
                u64* dq = (u64*)(rnxt + sh);
                ST_AG(dq, v0);
                ST_AG(dq + 1, v1);
            }
            asm volatile("s_waitcnt vmcnt(0)" ::: "memory");
            if (tid == 0)
                ST_AG(&flags_s[(size_t)c * 16], (unsigned)(t + 1));
        }

        // out/tail stores off the serial chain
        __builtin_nontemporal_store(hn, &out[(size_t)t * BB * NHH + (size_t)mrow * NHH + jcol]);
        if (t == TT - 1) {
            float* tail = out + (size_t)TT * BB * NHH;
            tail[(size_t)mrow * NHH + jcol]                    = hn;
            tail[(size_t)BB * NHH + (size_t)mrow * NHH + jcol] = cstate;
        }

        // prefetch next step's gx during the slack
        if (mode == 2 && t + 1 < TT) {
            const short* gsl = gx + ((((size_t)(t + 1) * 2 + s) * 128 + c) * 2 + mi2) * 512;
            #pragma unroll
            for (int g = 0; g < 4; ++g) gxv[g] = bf2f(gsl[(size_t)lanes[g] * 8 + es[g]]);
        }
    }
}

extern "C" void kernel_launch(void* const* d_in, const int* in_sizes, int n_in,
                              void* d_out, int out_size, void* d_ws, size_t ws_size,
                              hipStream_t stream) {
    const float* inputs = (const float*)d_in[0];
    const float* Wxf = (const float*)d_in[1],  *Whf = (const float*)d_in[2],  *bf = (const float*)d_in[3];
    const float* Wxi = (const float*)d_in[4],  *Whi = (const float*)d_in[5],  *bi = (const float*)d_in[6];
    const float* Wxc = (const float*)d_in[7],  *Whc = (const float*)d_in[8],  *bc = (const float*)d_in[9];
    const float* Wxo = (const float*)d_in[10], *Who = (const float*)d_in[11], *bo = (const float*)d_in[12];

    float* out = (float*)d_out;
    char*  wsb = (char*)d_ws;

    short*    wpk   = (short*)wsb;
    unsigned* flags = (unsigned*)(wsb + WPK_BYTES);
    short*    hpp   = (short*)(wsb + WPK_BYTES + FLG_BYTES);
    short*    xpk   = (short*)(wsb + WPK_BYTES + FLG_BYTES + HPP_BYTES);
    short*    gx    = (short*)(wsb + WPK_BYTES + FLG_BYTES + HPP_BYTES + XPK_BYTES);

    const size_t needT1 = WPK_BYTES + FLG_BYTES + HPP_BYTES + XPK_BYTES;
    const size_t needT0 = needT1 + GX_BYTES;
    const int mode = (ws_size >= needT0) ? 2 : (ws_size >= needT1) ? 1 : 0;

    // zero flags + H ping-pong every launch (graph replays rerun this)
    hipMemsetAsync(flags, 0, FLG_BYTES + HPP_BYTES, stream);

    pack_weights_kernel<<<dim3(128), dim3(256), 0, stream>>>(
        Wxf, Whf, Wxi, Whi, Wxc, Whc, Wxo, Who, wpk);

    if (mode >= 1)
        pack_x_kernel<<<dim3(TT), dim3(256), 0, stream>>>(inputs, xpk);

    if (mode == 2) {
        xproj_gemm<<<dim3(512), dim3(512), 0, stream>>>(xpk, wpk, gx);
        // xpk is now dead -> becomes the H ring; zero ring[0] (H0 = 0)
        hipMemsetAsync(xpk, 0, 131072, stream);
    }

    lstm_persistent<<<dim3(NBLK), dim3(256), 0, stream>>>(
        inputs, xpk, wpk, gx, bf, bi, bc, bo, out, hpp, xpk /*ring*/, flags, mode);
}

// Round 15
// 2629.216 us; speedup vs baseline: 1.2710x; 1.2710x over previous
//
#include <hip/hip_runtime.h>
#include <hip/hip_bf16.h>

#define TT  512
#define BB  64
#define NII 1024
#define NHH 1024
#define NBLK 256

typedef __attribute__((ext_vector_type(8))) short bf16x8;
typedef __attribute__((ext_vector_type(4))) float f32x4;
typedef unsigned long long u64;

// ws layout: [wpk 16M][flags 16K][hpp 256K][xpk/ring 64M][gx 256M]
// xpk doubles as the H ring after xproj_gemm consumes it (verified r12).
#define WPK_BYTES  (16ull << 20)
#define FLG_BYTES  (16384ull)
#define HPP_BYTES  (256ull << 10)
#define XPK_BYTES  (64ull << 20)
#define GX_BYTES   (256ull << 20)
#define HBUF_SHORTS 32768ull

#define MFMA16 __builtin_amdgcn_mfma_f32_16x16x32_bf16
#define LD_AG(p)    __hip_atomic_load((p),  __ATOMIC_RELAXED, __HIP_MEMORY_SCOPE_AGENT)
#define ST_AG(p, v) __hip_atomic_store((p), (v), __ATOMIC_RELAXED, __HIP_MEMORY_SCOPE_AGENT)

__device__ __forceinline__ float fast_sigmoid(float x) {
    return __builtin_amdgcn_rcpf(1.0f + __expf(-x));
}
__device__ __forceinline__ float fast_tanh(float x) {
    float e = __expf(2.0f * x);
    return 1.0f - 2.0f * __builtin_amdgcn_rcpf(e + 1.0f);
}
__device__ __forceinline__ short f2bf(float f) {
    union { __hip_bfloat16 b; short s; } u; u.b = __float2bfloat16(f); return u.s;
}
__device__ __forceinline__ float bf2f(short h) {
    union { unsigned u; float f; } v; v.u = ((unsigned)(unsigned short)h) << 16; return v.f;
}

// pipelined coherent 16B load (modes 0/1 fallback only)
__device__ __forceinline__ bf16x8 ld_coh16(const short* p) {
    const u64* q = (const u64*)p;
    u64 a = LD_AG(q);
    u64 b = LD_AG(q + 1);
    union { u64 u[2]; bf16x8 v; } u;
    u.u[0] = a; u.u[1] = b; return u.v;
}

// ---------------------------------------------------------------------------
// Pack weights, B-fragment-major bf16, 32 gate-cols per c-block (verified r8-r14).
// ---------------------------------------------------------------------------
__global__ __launch_bounds__(256)
void pack_weights_kernel(const float* __restrict__ Wxf, const float* __restrict__ Whf,
                         const float* __restrict__ Wxi, const float* __restrict__ Whi,
                         const float* __restrict__ Wxc, const float* __restrict__ Whc,
                         const float* __restrict__ Wxo, const float* __restrict__ Who,
                         short* __restrict__ wpk)
{
    const int c = blockIdx.x;
    const int t = threadIdx.x;
    const float* Wx[4] = { Wxf, Wxi, Wxc, Wxo };
    const float* Wh[4] = { Whf, Whi, Whc, Who };

    for (int i = 0; i < 32; ++i) {
        const int d   = t + i * 256;
        const int kkf = d >> 7;
        const int nt  = (d >> 6) & 1;
        const int l   = d & 63;
        const int n   = nt * 16 + (l & 15);
        const int g   = n >> 3;
        const int col = c * 8 + (n & 7);
        const int kf0 = kkf * 32 + (l >> 4) * 8;
        const float* src = (kf0 < 1024) ? (Wx[g] + (size_t)kf0 * NHH + col)
                                        : (Wh[g] + (size_t)(kf0 - 1024) * NHH + col);
        short v[8];
        #pragma unroll
        for (int e = 0; e < 8; ++e) v[e] = f2bf(src[(size_t)e * NHH]);
        *reinterpret_cast<bf16x8*>(wpk + ((size_t)c * 8192 + d) * 8) =
            *reinterpret_cast<bf16x8*>(v);
    }
}

// ---------------------------------------------------------------------------
// Pack x into per-half A-fragments (verified r8-r14).
// ---------------------------------------------------------------------------
__global__ __launch_bounds__(256)
void pack_x_kernel(const float* __restrict__ x, short* __restrict__ xpk)
{
    const int t = blockIdx.x;
    const float* xt = x + (size_t)t * BB * NII;
    short* dst = xpk + (size_t)t * 65536;

    for (int i = 0; i < 32; ++i) {
        const int d  = threadIdx.x + i * 256;
        const int s  = d >> 12;
        const int mi = (d >> 11) & 1;
        const int kk = (d >> 6) & 31;
        const int l  = d & 63;
        const int m  = s * 32 + mi * 16 + (l & 15);
        const int k0 = kk * 32 + ((l >> 4) << 3);
        const float* sp = xt + (size_t)m * NII + k0;
        f32x4 a0 = *reinterpret_cast<const f32x4*>(sp);
        f32x4 a1 = *reinterpret_cast<const f32x4*>(sp + 4);
        short v[8];
        #pragma unroll
        for (int e = 0; e < 4; ++e) { v[e] = f2bf(a0[e]); v[4 + e] = f2bf(a1[e]); }
        *reinterpret_cast<bf16x8*>(dst + (size_t)d * 8) = *reinterpret_cast<bf16x8*>(v);
    }
}

// ---------------------------------------------------------------------------
// x_proj GEMM v4 (round 15): 256 blocks = 64 c-pairs x 4 t-groups, 512 thr.
// Both c's x-half weights staged in 128 KiB LDS; 8 waves = 4 (s,mi) quarters
// x 2 t-halves (2 waves/SIMD for latency hiding). Fused-cc inner loop: each
// A-fragment pair feeds 8 MFMAs (both c's) -> A read ONCE per (t, wave).
// A-traffic 8 GB (r12) -> 4 GB; W-traffic 32 MB. Output layout identical
// to the verified r10/r12 gx (c = cp*2 + cc).
// ---------------------------------------------------------------------------
__global__ __launch_bounds__(512)
void xproj_gemm(const short* __restrict__ xpk, const short* __restrict__ wpk,
                short* __restrict__ gx)
{
    __shared__ short lds_wx[65536];   // 128 KiB: x-half weights of c-pair

    const int tid = threadIdx.x;
    const int w7 = tid >> 6, l = tid & 63;
    const int cp = blockIdx.x & 63, tg = blockIdx.x >> 6;   // 64 cpairs x 4 tg
    const int q  = w7 & 3;            // (s*2 + mi)
    const int th = w7 >> 2;           // t-half within the 128-t group
    const int s = q >> 1, mi = q & 1;

    // stage x-half weights of both c's: 8192 chunks of 16B / 512 threads
    {
        #pragma unroll
        for (int i = 0; i < 16; ++i) {
            const int ch  = tid + i * 512;       // 0..8191
            const int cc  = ch >> 12;            // 0..1
            const int off = ch & 4095;           // chunk within c's x-half
            *reinterpret_cast<bf16x8*>(&lds_wx[((size_t)cc * 4096 + off) * 8]) =
                *reinterpret_cast<const bf16x8*>(
                    wpk + ((size_t)(cp * 2 + cc) * 8192 + off) * 8);
        }
    }
    __syncthreads();

    for (int tt = 0; tt < 64; ++tt) {
        const int t = tg * 128 + th * 64 + tt;
        const short* ap = xpk + (size_t)t * 65536
                        + ((size_t)(q * 32) * 64 + l) * 8;
        const short* wl0 = &lds_wx[(size_t)l * 8];
        const short* wl1 = &lds_wx[(size_t)32768 + (size_t)l * 8];

        f32x4 c000 = {0,0,0,0}, c001 = {0,0,0,0}, c010 = {0,0,0,0}, c011 = {0,0,0,0};
        f32x4 c100 = {0,0,0,0}, c101 = {0,0,0,0}, c110 = {0,0,0,0}, c111 = {0,0,0,0};

        #pragma unroll 2
        for (int kk = 0; kk < 32; kk += 2) {
            bf16x8 A0 = *reinterpret_cast<const bf16x8*>(ap);
            bf16x8 A1 = *reinterpret_cast<const bf16x8*>(ap + 512);
            bf16x8 B000 = *reinterpret_cast<const bf16x8*>(wl0);
            bf16x8 B001 = *reinterpret_cast<const bf16x8*>(wl0 + 512);
            bf16x8 B010 = *reinterpret_cast<const bf16x8*>(wl0 + 1024);
            bf16x8 B011 = *reinterpret_cast<const bf16x8*>(wl0 + 1536);
            bf16x8 B100 = *reinterpret_cast<const bf16x8*>(wl1);
            bf16x8 B101 = *reinterpret_cast<const bf16x8*>(wl1 + 512);
            bf16x8 B110 = *reinterpret_cast<const bf16x8*>(wl1 + 1024);
            bf16x8 B111 = *reinterpret_cast<const bf16x8*>(wl1 + 1536);
            c000 = MFMA16(A0, B000, c000, 0, 0, 0);
            c001 = MFMA16(A0, B001, c001, 0, 0, 0);
            c010 = MFMA16(A1, B010, c010, 0, 0, 0);
            c011 = MFMA16(A1, B011, c011, 0, 0, 0);
            c100 = MFMA16(A0, B100, c100, 0, 0, 0);
            c101 = MFMA16(A0, B101, c101, 0, 0, 0);
            c110 = MFMA16(A1, B110, c110, 0, 0, 0);
            c111 = MFMA16(A1, B111, c111, 0, 0, 0);
            ap += 1024; wl0 += 2048; wl1 += 2048;
        }

        short o[8];
        // cc = 0
        o[0] = f2bf(c000[0] + c010[0]); o[1] = f2bf(c000[1] + c010[1]);
        o[2] = f2bf(c000[2] + c010[2]); o[3] = f2bf(c000[3] + c010[3]);
        o[4] = f2bf(c001[0] + c011[0]); o[5] = f2bf(c001[1] + c011[1]);
        o[6] = f2bf(c001[2] + c011[2]); o[7] = f2bf(c001[3] + c011[3]);
        short* dst0 = gx + ((((size_t)t * 2 + s) * 128 + (size_t)(cp * 2)) * 2 + mi) * 512
                    + (size_t)l * 8;
        *reinterpret_cast<bf16x8*>(dst0) = *reinterpret_cast<bf16x8*>(o);
        // cc = 1
        o[0] = f2bf(c100[0] + c110[0]); o[1] = f2bf(c100[1] + c110[1]);
        o[2] = f2bf(c100[2] + c110[2]); o[3] = f2bf(c100[3] + c110[3]);
        o[4] = f2bf(c101[0] + c111[0]); o[5] = f2bf(c101[1] + c111[1]);
        o[6] = f2bf(c101[2] + c111[2]); o[7] = f2bf(c101[3] + c111[3]);
        short* dst1 = gx + ((((size_t)t * 2 + s) * 128 + (size_t)(cp * 2 + 1)) * 2 + mi) * 512
                    + (size_t)l * 8;
        *reinterpret_cast<bf16x8*>(dst1) = *reinterpret_cast<bf16x8*>(o);
    }
}

// ---------------------------------------------------------------------------
// x-half compute (modes 0/1 fallback; verified r9-r12).
// ---------------------------------------------------------------------------
__device__ __forceinline__ void compute_x_half(
    int t, int mi, int l, int s, int use_xpk,
    const float* __restrict__ x, const short* __restrict__ xpk,
    const short* lds_w, float* rdst)
{
    f32x4 a00 = {0,0,0,0}, a01 = {0,0,0,0}, a10 = {0,0,0,0}, a11 = {0,0,0,0};
    const short* wl = lds_w + (size_t)l * 8;
    if (use_xpk) {
        const short* ap = xpk + (size_t)t * 65536
                        + (((size_t)(s * 2 + mi)) * 32) * 512 + (size_t)l * 8;
        #pragma unroll 4
        for (int kk = 0; kk < 32; kk += 2) {
            bf16x8 A0  = *reinterpret_cast<const bf16x8*>(ap);
            bf16x8 B00 = *reinterpret_cast<const bf16x8*>(wl);
            bf16x8 B01 = *reinterpret_cast<const bf16x8*>(wl + 512);
            bf16x8 A1  = *reinterpret_cast<const bf16x8*>(ap + 512);
            bf16x8 B10 = *reinterpret_cast<const bf16x8*>(wl + 1024);
            bf16x8 B11 = *reinterpret_cast<const bf16x8*>(wl + 1536);
            a00 = MFMA16(A0, B00, a00, 0, 0, 0);
            a01 = MFMA16(A0, B01, a01, 0, 0, 0);
            a10 = MFMA16(A1, B10, a10, 0, 0, 0);
            a11 = MFMA16(A1, B11, a11, 0, 0, 0);
            ap += 1024; wl += 2048;
        }
    } else {
        const float* apf = x + ((size_t)t * BB + (size_t)(s * 32 + mi * 16 + (l & 15))) * NII
                         + ((l >> 4) << 3);
        #pragma unroll 4
        for (int kk = 0; kk < 32; kk += 2) {
            f32x4 f0 = *reinterpret_cast<const f32x4*>(apf);
            f32x4 f1 = *reinterpret_cast<const f32x4*>(apf + 4);
            bf16x8 B00 = *reinterpret_cast<const bf16x8*>(wl);
            bf16x8 B01 = *reinterpret_cast<const bf16x8*>(wl + 512);
            f32x4 f2 = *reinterpret_cast<const f32x4*>(apf + 32);
            f32x4 f3 = *reinterpret_cast<const f32x4*>(apf + 36);
            bf16x8 B10 = *reinterpret_cast<const bf16x8*>(wl + 1024);
            bf16x8 B11 = *reinterpret_cast<const bf16x8*>(wl + 1536);
            bf16x8 A0, A1;
            A0[0]=f2bf(f0[0]); A0[1]=f2bf(f0[1]); A0[2]=f2bf(f0[2]); A0[3]=f2bf(f0[3]);
            A0[4]=f2bf(f1[0]); A0[5]=f2bf(f1[1]); A0[6]=f2bf(f1[2]); A0[7]=f2bf(f1[3]);
            A1[0]=f2bf(f2[0]); A1[1]=f2bf(f2[1]); A1[2]=f2bf(f2[2]); A1[3]=f2bf(f2[3]);
            A1[4]=f2bf(f3[0]); A1[5]=f2bf(f3[1]); A1[6]=f2bf(f3[2]); A1[7]=f2bf(f3[3]);
            a00 = MFMA16(A0, B00, a00, 0, 0, 0);
            a01 = MFMA16(A0, B01, a01, 0, 0, 0);
            a10 = MFMA16(A1, B10, a10, 0, 0, 0);
            a11 = MFMA16(A1, B11, a11, 0, 0, 0);
            apf += 64; wl += 2048;
        }
    }
    rdst[0] = a00[0] + a10[0]; rdst[1] = a00[1] + a10[1];
    rdst[2] = a00[2] + a10[2]; rdst[3] = a00[3] + a10[3];
    rdst[4] = a01[0] + a11[0]; rdst[5] = a01[1] + a11[1];
    rdst[6] = a01[2] + a11[2]; rdst[7] = a01[3] + a11[3];
}

// ---------------------------------------------------------------------------
// Persistent LSTM — byte-identical to round 12 (best verified: 2.09 ms).
// ---------------------------------------------------------------------------
__global__ __launch_bounds__(256, 1)
void lstm_persistent(const float* __restrict__ x,
                     const short* __restrict__ xpk,
                     const short* __restrict__ wpk,
                     const short* __restrict__ gx,
                     const float* __restrict__ bfv, const float* __restrict__ biv,
                     const float* __restrict__ bcv, const float* __restrict__ bov,
                     float* __restrict__ out,
                     short* hpp,
                     short* ring,
                     unsigned* flags,
                     int mode)
{
    __shared__ short lds_w[64 * 2 * 64 * 8];   // 128 KiB weights
    __shared__ float redx[2][2][64][8];        // modes 0/1 only
    __shared__ float redh[4][64][8];
    __shared__ short hstage[256];
    __shared__ int   lds_epoch;

    const int tid = threadIdx.x;
    const int w   = tid >> 6;
    const int l   = tid & 63;
    const int c   = blockIdx.x >> 1;
    const int s   = blockIdx.x & 1;

    unsigned* flags_s = flags + s * 2048;      // 128 flags x 64 B stride

    if (mode == 2) {
        const short* wsrc = wpk + (size_t)c * 65536 + 32768;   // h-half only
        #pragma unroll
        for (int i = 0; i < 16; ++i) {
            const int ch = tid + i * 256;
            *reinterpret_cast<bf16x8*>(&lds_w[(size_t)ch * 8]) =
                *reinterpret_cast<const bf16x8*>(&wsrc[(size_t)ch * 8]);
        }
    } else {
        const short* wsrc = wpk + (size_t)c * 65536;
        #pragma unroll
        for (int i = 0; i < 32; ++i) {
            const int ch = tid + i * 256;
            *reinterpret_cast<bf16x8*>(&lds_w[(size_t)ch * 8]) =
                *reinterpret_cast<const bf16x8*>(&wsrc[(size_t)ch * 8]);
        }
    }
    if (tid == 0) lds_epoch = -1;

    const int m_loc = tid >> 3;
    const int jc    = tid & 7;
    const int mi2   = m_loc >> 4, ml = m_loc & 15;
    const int lb    = (ml >> 2) << 4, lr = ml & 3;
    const int jcol  = c * 8 + jc;
    const int mrow  = s * 32 + m_loc;
    int lanes[4], es[4];
    #pragma unroll
    for (int g = 0; g < 4; ++g) { lanes[g] = lb + (g & 1) * 8 + jc; es[g] = (g >> 1) * 4 + lr; }

    float B4[4];
    B4[0] = bfv[jcol]; B4[1] = biv[jcol]; B4[2] = bcv[jcol]; B4[3] = bov[jcol];
    float cstate = 0.0f;
    __syncthreads();

    // prologues
    float gxv[4] = {0.f, 0.f, 0.f, 0.f};
    if (mode == 2) {
        const short* gsl = gx + ((((size_t)0 * 2 + s) * 128 + c) * 2 + mi2) * 512;
        #pragma unroll
        for (int g = 0; g < 4; ++g) gxv[g] = bf2f(gsl[(size_t)lanes[g] * 8 + es[g]]);
    } else if (w < 2) {
        compute_x_half(0, w & 1, l, s, mode, x, xpk, lds_w, &redx[0][w & 1][l][0]);
    }

    #pragma unroll 1
    for (int t = 0; t < TT; ++t) {
        const short* rcur = (mode == 2)
            ? ring + (size_t)t * 65536 + (size_t)s * 32768
            : hpp + ((size_t)((t & 1) * 2 + s)) * HBUF_SHORTS;
        short* rnxt = (mode == 2)
            ? ring + (size_t)(t + 1) * 65536 + (size_t)s * 32768
            : hpp + ((size_t)(((t + 1) & 1) * 2 + s)) * HBUF_SHORTS;

        if (mode == 2) {
            if (w == 2) {
                const unsigned tv = (unsigned)t;
                for (;;) {
                    unsigned v0 = LD_AG(flags_s + (size_t)l * 16);
                    unsigned v1 = LD_AG(flags_s + (size_t)(l + 64) * 16);
                    if (__all((v0 >= tv) & (v1 >= tv))) break;
                    __builtin_amdgcn_s_sleep(1);
                }
                if (l == 0) *((volatile int*)&lds_epoch) = t;
            } else {
                while (*((volatile int*)&lds_epoch) < t) { }
            }
            asm volatile("" ::: "memory");   // keep H loads below the wait

            const int mi = w & 1, ki = w >> 1;
            f32x4 a00 = {0,0,0,0}, a01 = {0,0,0,0}, a10 = {0,0,0,0}, a11 = {0,0,0,0};
            const short* ap = rcur + ((size_t)(mi * 32 + ki * 16) * 64 + l) * 8;
            const short* wl = &lds_w[(size_t)ki * 16384 + (size_t)l * 8];
            #pragma unroll 4
            for (int kk = 0; kk < 16; kk += 2) {
                bf16x8 A0  = *reinterpret_cast<const bf16x8*>(ap);        // plain cached
                bf16x8 B00 = *reinterpret_cast<const bf16x8*>(wl);
                bf16x8 B01 = *reinterpret_cast<const bf16x8*>(wl + 512);
                bf16x8 A1  = *reinterpret_cast<const bf16x8*>(ap + 512);  // plain cached
                bf16x8 B10 = *reinterpret_cast<const bf16x8*>(wl + 1024);
                bf16x8 B11 = *reinterpret_cast<const bf16x8*>(wl + 1536);
                a00 = MFMA16(A0, B00, a00, 0, 0, 0);
                a01 = MFMA16(A0, B01, a01, 0, 0, 0);
                a10 = MFMA16(A1, B10, a10, 0, 0, 0);
                a11 = MFMA16(A1, B11, a11, 0, 0, 0);
                ap += 1024; wl += 2048;
            }
            float* r = &redh[w][l][0];
            r[0] = a00[0] + a10[0]; r[1] = a00[1] + a10[1];
            r[2] = a00[2] + a10[2]; r[3] = a00[3] + a10[3];
            r[4] = a01[0] + a11[0]; r[5] = a01[1] + a11[1];
            r[6] = a01[2] + a11[2]; r[7] = a01[3] + a11[3];
        } else if (w >= 2) {
            const int mi = w & 1;
            if (mi == 0) {
                const unsigned tv = (unsigned)t;
                for (;;) {
                    unsigned v0 = LD_AG(flags_s + (size_t)l * 16);
                    unsigned v1 = LD_AG(flags_s + (size_t)(l + 64) * 16);
                    if (__all((v0 >= tv) & (v1 >= tv))) break;
                    __builtin_amdgcn_s_sleep(1);
                }
                if (l == 0) *((volatile int*)&lds_epoch) = t;
            } else {
                while (*((volatile int*)&lds_epoch) < t) { }
            }
            asm volatile("" ::: "memory");

            f32x4 a00 = {0,0,0,0}, a01 = {0,0,0,0}, a10 = {0,0,0,0}, a11 = {0,0,0,0};
            const short* ap = rcur + ((size_t)(mi * 32)) * 512 + (size_t)l * 8;
            const short* wl = &lds_w[(size_t)32768 + (size_t)l * 8];
            #pragma unroll 4
            for (int kk = 0; kk < 32; kk += 2) {
                bf16x8 A0  = ld_coh16(ap);
                bf16x8 B00 = *reinterpret_cast<const bf16x8*>(wl);
                bf16x8 B01 = *reinterpret_cast<const bf16x8*>(wl + 512);
                bf16x8 A1  = ld_coh16(ap + 512);
                bf16x8 B10 = *reinterpret_cast<const bf16x8*>(wl + 1024);
                bf16x8 B11 = *reinterpret_cast<const bf16x8*>(wl + 1536);
                a00 = MFMA16(A0, B00, a00, 0, 0, 0);
                a01 = MFMA16(A0, B01, a01, 0, 0, 0);
                a10 = MFMA16(A1, B10, a10, 0, 0, 0);
                a11 = MFMA16(A1, B11, a11, 0, 0, 0);
                ap += 1024; wl += 2048;
            }
            float* r = &redh[2 + mi][l][0];
            r[0] = a00[0] + a10[0]; r[1] = a00[1] + a10[1];
            r[2] = a00[2] + a10[2]; r[3] = a00[3] + a10[3];
            r[4] = a01[0] + a11[0]; r[5] = a01[1] + a11[1];
            r[6] = a01[2] + a11[2]; r[7] = a01[3] + a11[3];
        } else {
            if (t + 1 < TT)
                compute_x_half(t + 1, w & 1, l, s, mode, x, xpk, lds_w,
                               &redx[(t + 1) & 1][w & 1][l][0]);
        }
        __syncthreads();

        // epilogue
        float gv[4];
        #pragma unroll
        for (int g = 0; g < 4; ++g) {
            const int lane = lanes[g], e = es[g];
            float xterm = (mode == 2) ? (gxv[g] + redh[mi2][lane][e])
                                      : redx[t & 1][mi2][lane][e];
            gv[g] = xterm + redh[2 + mi2][lane][e] + B4[g];
        }
        const float F  = fast_sigmoid(gv[0]);
        const float I  = fast_sigmoid(gv[1]);
        const float Ct = fast_tanh(gv[2]);
        const float O  = fast_sigmoid(gv[3]);
        cstate = F * cstate + I * Ct;
        const float hn = O * fast_tanh(cstate);
        hstage[tid] = f2bf(hn);
        __syncthreads();

        // wave0 publishes packed H + flag (protocol verified r3-r12)
        if (w == 0 && t < TT - 1) {
            if (l < 32) {
                const int mi3 = l >> 4, ml3 = l & 15;
                const u64 v0 = ((const u64*)hstage)[l * 2];
                const u64 v1 = ((const u64*)hstage)[l * 2 + 1];
                const size_t sh = ((size_t)(mi3 * 32 + (c >> 2)) * 64
                                   + (size_t)((c & 3) * 16 + ml3)) * 8;
                u64* dq = (u64*)(rnxt + sh);
                ST_AG(dq, v0);
                ST_AG(dq + 1, v1);
            }
            asm volatile("s_waitcnt vmcnt(0)" ::: "memory");
            if (tid == 0)
                ST_AG(&flags_s[(size_t)c * 16], (unsigned)(t + 1));
        }

        // out/tail stores off the serial chain
        __builtin_nontemporal_store(hn, &out[(size_t)t * BB * NHH + (size_t)mrow * NHH + jcol]);
        if (t == TT - 1) {
            float* tail = out + (size_t)TT * BB * NHH;
            tail[(size_t)mrow * NHH + jcol]                    = hn;
            tail[(size_t)BB * NHH + (size_t)mrow * NHH + jcol] = cstate;
        }

        // prefetch next step's gx during the slack
        if (mode == 2 && t + 1 < TT) {
            const short* gsl = gx + ((((size_t)(t + 1) * 2 + s) * 128 + c) * 2 + mi2) * 512;
            #pragma unroll
            for (int g = 0; g < 4; ++g) gxv[g] = bf2f(gsl[(size_t)lanes[g] * 8 + es[g]]);
        }
    }
}

extern "C" void kernel_launch(void* const* d_in, const int* in_sizes, int n_in,
                              void* d_out, int out_size, void* d_ws, size_t ws_size,
                              hipStream_t stream) {
    const float* inputs = (const float*)d_in[0];
    const float* Wxf = (const float*)d_in[1],  *Whf = (const float*)d_in[2],  *bf = (const float*)d_in[3];
    const float* Wxi = (const float*)d_in[4],  *Whi = (const float*)d_in[5],  *bi = (const float*)d_in[6];
    const float* Wxc = (const float*)d_in[7],  *Whc = (const float*)d_in[8],  *bc = (const float*)d_in[9];
    const float* Wxo = (const float*)d_in[10], *Who = (const float*)d_in[11], *bo = (const float*)d_in[12];

    float* out = (float*)d_out;
    char*  wsb = (char*)d_ws;

    short*    wpk   = (short*)wsb;
    unsigned* flags = (unsigned*)(wsb + WPK_BYTES);
    short*    hpp   = (short*)(wsb + WPK_BYTES + FLG_BYTES);
    short*    xpk   = (short*)(wsb + WPK_BYTES + FLG_BYTES + HPP_BYTES);
    short*    gx    = (short*)(wsb + WPK_BYTES + FLG_BYTES + HPP_BYTES + XPK_BYTES);

    const size_t needT1 = WPK_BYTES + FLG_BYTES + HPP_BYTES + XPK_BYTES;
    const size_t needT0 = needT1 + GX_BYTES;
    const int mode = (ws_size >= needT0) ? 2 : (ws_size >= needT1) ? 1 : 0;

    // zero flags + H ping-pong every launch (graph replays rerun this)
    hipMemsetAsync(flags, 0, FLG_BYTES + HPP_BYTES, stream);

    pack_weights_kernel<<<dim3(128), dim3(256), 0, stream>>>(
        Wxf, Whf, Wxi, Whi, Wxc, Whc, Wxo, Who, wpk);

    if (mode >= 1)
        pack_x_kernel<<<dim3(TT), dim3(256), 0, stream>>>(inputs, xpk);

    if (mode == 2) {
        xproj_gemm<<<dim3(256), dim3(512), 0, stream>>>(xpk, wpk, gx);
        // xpk is now dead -> becomes the H ring; zero ring[0] (H0 = 0)
        hipMemsetAsync(xpk, 0, 131072, stream);
    }

    lstm_persistent<<<dim3(NBLK), dim3(256), 0, stream>>>(
        inputs, xpk, wpk, gx, bf, bi, bc, bo, out, hpp, xpk /*ring*/, flags, mode);
}